// Round 1
// baseline (1103.234 us; speedup 1.0000x reference)
//
// Round 1: correctness-first hybrid fp32/bf16 implementation.
// - fp32 (exact) through attention + rms1 + router => routing matches reference.
// - bf16 MFMA (16x16x32) for expert/shared FFN (90% of FLOPs), post-routing.
// Requires ws_size >= ~381 MB.
#include <hip/hip_runtime.h>
#include <math.h>

#define TOK   4096
#define SEQL  1024
#define HID   512
#define NEXP  64
#define FFI   1536
#define NTOPK 6

typedef short bf16x8v __attribute__((ext_vector_type(8)));
typedef float f32x4   __attribute__((ext_vector_type(4)));

__device__ __forceinline__ unsigned short f2bf(float f){
  unsigned int u = __float_as_uint(f);
  u += 0x7fffu + ((u >> 16) & 1u);
  return (unsigned short)(u >> 16);
}
__device__ __forceinline__ float bf2f(unsigned short s){
  return __uint_as_float(((unsigned int)s) << 16);
}

// ---------------- fp32 transpose (out[c][r] = in[r][c]) ----------------
__global__ __launch_bounds__(256) void ktranspose(const float* __restrict__ in,
                                                  float* __restrict__ out, int R, int C){
  __shared__ float tile[32][33];
  int c0 = blockIdx.x * 32, r0 = blockIdx.y * 32;
  int tx = threadIdx.x & 31, ty = threadIdx.x >> 5; // ty 0..7
  #pragma unroll
  for (int i = 0; i < 4; i++) tile[ty + i*8][tx] = in[(long long)(r0 + ty + i*8) * C + c0 + tx];
  __syncthreads();
  #pragma unroll
  for (int i = 0; i < 4; i++) out[(long long)(c0 + ty + i*8) * R + r0 + tx] = tile[tx][ty + i*8];
}

// ---------------- fp32 TN GEMM: C[m][n] = alpha * sum_k A[m][k]*B[n][k] ----------------
// 64x64 tile, BK=16, 256 threads, 4x4 micro-tile. M,N mult of 64; K mult of 16.
__global__ __launch_bounds__(256) void gemm_f32(
    const float* __restrict__ A, const float* __restrict__ B, float* __restrict__ C,
    int K, int lda, int ldb, int ldc, float alpha,
    long long a1, long long a2, int adiv,
    long long b1, long long b2, int bdiv,
    long long c1, long long c2, int cdiv)
{
  int z = blockIdx.z;
  A += (long long)(z / adiv) * a1 + (long long)(z % adiv) * a2;
  B += (long long)(z / bdiv) * b1 + (long long)(z % bdiv) * b2;
  C += (long long)(z / cdiv) * c1 + (long long)(z % cdiv) * c2;
  int m0 = blockIdx.x * 64, n0 = blockIdx.y * 64;
  __shared__ float As[16][68];
  __shared__ float Bs[16][68];
  int tid = threadIdx.x;
  int row = tid >> 2, kq = (tid & 3) * 4;
  int ty = tid >> 4, tx = tid & 15;
  float acc[4][4] = {};
  for (int k0 = 0; k0 < K; k0 += 16){
    float4 av = *(const float4*)&A[(long long)(m0 + row) * lda + k0 + kq];
    float4 bv = *(const float4*)&B[(long long)(n0 + row) * ldb + k0 + kq];
    __syncthreads();
    As[kq+0][row] = av.x; As[kq+1][row] = av.y; As[kq+2][row] = av.z; As[kq+3][row] = av.w;
    Bs[kq+0][row] = bv.x; Bs[kq+1][row] = bv.y; Bs[kq+2][row] = bv.z; Bs[kq+3][row] = bv.w;
    __syncthreads();
    #pragma unroll
    for (int k = 0; k < 16; k++){
      float4 a4 = *(const float4*)&As[k][ty*4];
      float4 b4 = *(const float4*)&Bs[k][tx*4];
      float aa[4] = {a4.x, a4.y, a4.z, a4.w};
      float bb[4] = {b4.x, b4.y, b4.z, b4.w};
      #pragma unroll
      for (int i = 0; i < 4; i++)
        #pragma unroll
        for (int j = 0; j < 4; j++) acc[i][j] += aa[i] * bb[j];
    }
  }
  #pragma unroll
  for (int i = 0; i < 4; i++){
    float4 o;
    o.x = acc[i][0]*alpha; o.y = acc[i][1]*alpha; o.z = acc[i][2]*alpha; o.w = acc[i][3]*alpha;
    *(float4*)&C[(long long)(m0 + ty*4 + i) * ldc + n0 + tx*4] = o;
  }
}

// ---------------- RoPE (in-place on q,k of qkv) + V^T write ----------------
__global__ __launch_bounds__(256) void krope(float* __restrict__ qkv, float* __restrict__ vT,
                                             const float* __restrict__ cosb, const float* __restrict__ sinb){
  int gid = blockIdx.x * 256 + threadIdx.x;   // TOK*8*32 threads
  int t = gid >> 8; int rem = gid & 255; int h = rem >> 5; int d = rem & 31;
  int s = t & (SEQL - 1);
  long long base = (long long)t * 1536 + h * 64;
  float c1 = cosb[s*64 + d], c2 = cosb[s*64 + d + 32];
  float s1 = sinb[s*64 + d], s2 = sinb[s*64 + d + 32];
  float q1 = qkv[base + d], q2 = qkv[base + d + 32];
  qkv[base + d]      = q1*c1 - q2*s1;
  qkv[base + d + 32] = q2*c2 + q1*s2;
  float k1 = qkv[base + 512 + d], k2 = qkv[base + 512 + d + 32];
  qkv[base + 512 + d]      = k1*c1 - k2*s1;
  qkv[base + 512 + d + 32] = k2*c2 + k1*s2;
  float v1 = qkv[base + 1024 + d], v2 = qkv[base + 1024 + d + 32];
  int b = t >> 10;
  long long vb = ((long long)(b*8 + h) * 64) * 1024 + s;
  vT[vb + (long long)d * 1024]        = v1;
  vT[vb + (long long)(d + 32) * 1024] = v2;
}

// ---------------- softmax over rows of 1024 (in place) ----------------
__global__ __launch_bounds__(256) void ksoftmax(float* __restrict__ sc){
  long long row = blockIdx.x;
  float* p = sc + row * 1024;
  int tid = threadIdx.x;
  float4 v = *(float4*)&p[tid*4];
  float m = fmaxf(fmaxf(v.x, v.y), fmaxf(v.z, v.w));
  for (int o = 32; o > 0; o >>= 1) m = fmaxf(m, __shfl_xor(m, o));
  __shared__ float redm[4], reds[4];
  int wid = tid >> 6, lane = tid & 63;
  if (lane == 0) redm[wid] = m;
  __syncthreads();
  m = fmaxf(fmaxf(redm[0], redm[1]), fmaxf(redm[2], redm[3]));
  float e0 = expf(v.x - m), e1 = expf(v.y - m), e2 = expf(v.z - m), e3 = expf(v.w - m);
  float sum = e0 + e1 + e2 + e3;
  for (int o = 32; o > 0; o >>= 1) sum += __shfl_xor(sum, o);
  if (lane == 0) reds[wid] = sum;
  __syncthreads();
  sum = reds[0] + reds[1] + reds[2] + reds[3];
  float inv = 1.0f / sum;
  float4 o4; o4.x = e0*inv; o4.y = e1*inv; o4.z = e2*inv; o4.w = e3*inv;
  *(float4*)&p[tid*4] = o4;
}

// ---------------- rms_norm(x + attn) -> h1 (f32), h1b (bf16), macc (f32) ----------------
__global__ __launch_bounds__(128) void krms1(const float* __restrict__ x, const float* __restrict__ attn,
    float* __restrict__ h1, unsigned short* __restrict__ h1b, float* __restrict__ macc){
  long long row = blockIdx.x;
  int tid = threadIdx.x;
  float4 xv = *(const float4*)&x[row*512 + tid*4];
  float4 av = *(const float4*)&attn[row*512 + tid*4];
  float4 v; v.x = xv.x+av.x; v.y = xv.y+av.y; v.z = xv.z+av.z; v.w = xv.w+av.w;
  float ss = v.x*v.x + v.y*v.y + v.z*v.z + v.w*v.w;
  for (int o = 32; o > 0; o >>= 1) ss += __shfl_xor(ss, o);
  __shared__ float red[2];
  int wid = tid >> 6, lane = tid & 63;
  if (lane == 0) red[wid] = ss;
  __syncthreads();
  ss = red[0] + red[1];
  float r = 1.0f / sqrtf(ss * (1.0f/512.0f) + 1e-5f);
  float4 o; o.x = v.x*r; o.y = v.y*r; o.z = v.z*r; o.w = v.w*r;
  *(float4*)&h1[row*512 + tid*4] = o;
  *(float4*)&macc[row*512 + tid*4] = o;
  ushort4 ob = make_ushort4(f2bf(o.x), f2bf(o.y), f2bf(o.z), f2bf(o.w));
  *(ushort4*)&h1b[row*512 + tid*4] = ob;
}

__global__ __launch_bounds__(128) void krms2(const float* __restrict__ macc, float* __restrict__ out){
  long long row = blockIdx.x;
  int tid = threadIdx.x;
  float4 v = *(const float4*)&macc[row*512 + tid*4];
  float ss = v.x*v.x + v.y*v.y + v.z*v.z + v.w*v.w;
  for (int o = 32; o > 0; o >>= 1) ss += __shfl_xor(ss, o);
  __shared__ float red[2];
  int wid = tid >> 6, lane = tid & 63;
  if (lane == 0) red[wid] = ss;
  __syncthreads();
  ss = red[0] + red[1];
  float r = 1.0f / sqrtf(ss * (1.0f/512.0f) + 1e-5f);
  float4 o; o.x = v.x*r; o.y = v.y*r; o.z = v.z*r; o.w = v.w*r;
  *(float4*)&out[row*512 + tid*4] = o;
}

// ---------------- routing: softmax, top-3 devices, top-6 experts, weights ----------------
__global__ __launch_bounds__(256) void krouter(const float* __restrict__ logits,
    float* __restrict__ probs, int* __restrict__ idx, float* __restrict__ wts, int* __restrict__ cnt){
  int t = blockIdx.x * 4 + (threadIdx.x >> 6);
  int e = threadIdx.x & 63;
  float l = logits[t*64 + e];
  float m = l;
  for (int o = 32; o > 0; o >>= 1) m = fmaxf(m, __shfl_xor(m, o));
  float p = expf(l - m);
  float s = p;
  for (int o = 32; o > 0; o >>= 1) s += __shfl_xor(s, o);
  p /= s;
  probs[t*64 + e] = p;
  float d = p;
  d += __shfl_xor(d, 1); d += __shfl_xor(d, 2); d += __shfl_xor(d, 4);
  int g = e >> 3;
  float mysc = d;
  int rank = 0;
  #pragma unroll
  for (int j = 0; j < 8; j++){
    float sj = __shfl(d, j*8);
    rank += (sj > mysc) || (sj == mysc && j < g);
  }
  float q = (rank < 3) ? p : -INFINITY;
  float svals[6]; int sidx[6];
  #pragma unroll
  for (int kk = 0; kk < 6; kk++){
    float v = q; int vi = e;
    for (int o = 32; o > 0; o >>= 1){
      float ov = __shfl_xor(v, o); int oi = __shfl_xor(vi, o);
      if (ov > v || (ov == v && oi < vi)){ v = ov; vi = oi; }
    }
    svals[kk] = v; sidx[kk] = vi;
    if (e == vi) q = -INFINITY;
  }
  float mx = svals[0], tot = 0.0f, wv[6];
  #pragma unroll
  for (int kk = 0; kk < 6; kk++){ wv[kk] = expf(svals[kk] - mx); tot += wv[kk]; }
  if (e < 6){
    idx[t*6 + e] = sidx[e];
    wts[t*6 + e] = wv[e] / tot;
    atomicAdd(&cnt[sidx[e]], 1);
  }
}

__global__ __launch_bounds__(256) void ksump(const float* __restrict__ probs, float* __restrict__ sumP){
  int e = blockIdx.x; int tid = threadIdx.x;
  float acc = 0.0f;
  for (int t = tid; t < TOK; t += 256) acc += probs[t*64 + e];
  for (int o = 32; o > 0; o >>= 1) acc += __shfl_xor(acc, o);
  __shared__ float red[4];
  int wid = tid >> 6, lane = tid & 63;
  if (lane == 0) red[wid] = acc;
  __syncthreads();
  if (tid == 0) sumP[e] = red[0] + red[1] + red[2] + red[3];
}

__global__ void kfinalize(const int* __restrict__ cnt, int* __restrict__ offs,
                          int2* __restrict__ tiles, int* __restrict__ ntl){
  if (threadIdx.x == 0){
    int acc = 0;
    for (int e = 0; e < 64; e++){ offs[e] = acc; acc += cnt[e]; }
    offs[64] = acc;
    int nt = 0;
    for (int e = 0; e < 64; e++){
      int me = cnt[e];
      for (int m0 = 0; m0 < me; m0 += 128){ tiles[nt] = make_int2(e, m0); nt++; }
    }
    *ntl = nt;
  }
}

__global__ __launch_bounds__(256) void kscatter(const int* __restrict__ idx, const float* __restrict__ wts,
    const int* __restrict__ offs, int* __restrict__ cursor, int* __restrict__ rowsl, float* __restrict__ wrowl){
  int g = blockIdx.x * 256 + threadIdx.x;
  if (g >= TOK * 6) return;
  int t = g / 6, kk = g % 6;
  int e = idx[t*6 + kk];
  int pos = atomicAdd(&cursor[e], 1);
  rowsl[offs[e] + pos] = t;
  wrowl[offs[e] + pos] = wts[t*6 + kk];
}

// ---------------- swiglu activation: hact[r][i] = silu(gu[r][i]) * gu[r][1536+i] ----------------
__global__ __launch_bounds__(256) void kact(const unsigned short* __restrict__ gu,
                                            unsigned short* __restrict__ hact, int total8){
  int g = blockIdx.x * 256 + threadIdx.x;
  if (g >= total8) return;
  int r = g / 192, c8 = (g % 192) * 8;
  const unsigned short* gp = gu + (long long)r * 3072 + c8;
  uint4 gv = *(const uint4*)gp;
  uint4 uv = *(const uint4*)(gp + 1536);
  const unsigned short* gs = (const unsigned short*)&gv;
  const unsigned short* us = (const unsigned short*)&uv;
  unsigned short hv[8] __attribute__((aligned(16)));
  #pragma unroll
  for (int j = 0; j < 8; j++){
    float xg = bf2f(gs[j]);
    float xu = bf2f(us[j]);
    float h = (xg / (1.0f + expf(-xg))) * xu;
    hv[j] = f2bf(h);
  }
  *(uint4*)(hact + (long long)r * 1536 + c8) = *(uint4*)hv;
}

// ---------------- bf16 MFMA GEMM, 128x128 tile, BK=32, 4 waves ----------------
// MODE 0: expert gate/up   (A = gathered h1b rows, B = r_wgu[e] f32, C = gu bf16)
// MODE 1: expert down      (A = hact contig rows, B = r_wd[e] f32, C = atomicAdd macc * wrow)
// MODE 2: shared gate/up   (A = h1b, z picks B/C, C = sgu bf16)
// MODE 3: shared down      (A = shact + z, B = s_wd[z], C = atomicAdd macc)
template<int MODE>
__global__ __launch_bounds__(256) void gemm_bf16(
    const unsigned short* __restrict__ Ab, const float* __restrict__ Bb,
    unsigned short* __restrict__ Cb, float* __restrict__ Cacc,
    const int* __restrict__ offs, const int2* __restrict__ tiles, const int* __restrict__ ntl,
    const int* __restrict__ rowsl, const float* __restrict__ wrowl,
    int N, int K)
{
  int e = 0, m0 = 0, roff = 0, Me = 1 << 30;
  long long Boff = 0;
  const unsigned short* A;
  int lda;
  if constexpr (MODE == 0 || MODE == 1){
    if (blockIdx.x >= *ntl) return;
    int2 tl = tiles[blockIdx.x];
    e = tl.x; m0 = tl.y;
    roff = offs[e]; Me = offs[e+1] - roff;
    Boff = (long long)e * K * N;
    if constexpr (MODE == 0){ A = Ab; lda = 512; }
    else { A = Ab + (long long)(roff + m0) * K; lda = K; }
  } else {
    m0 = blockIdx.x * 128;
    int z = blockIdx.z;
    Boff = (long long)z * K * N;
    if constexpr (MODE == 2){ A = Ab; lda = 512; }
    else { A = Ab + (long long)z * 4096 * K; lda = K; }
  }
  const float* B = Bb + Boff;
  int n0 = blockIdx.y * 128;

  __shared__ __align__(16) unsigned short As[128*40];
  __shared__ __align__(16) unsigned short Bs[128*40];

  int tid = threadIdx.x;
  int wid = tid >> 6, lane = tid & 63;
  int wr = wid >> 1, wc = wid & 1;
  int lrow = lane & 15, kgo = (lane >> 4) * 8;

  f32x4 acc[4][4];
  #pragma unroll
  for (int i = 0; i < 4; i++)
    #pragma unroll
    for (int j = 0; j < 4; j++) acc[i][j] = (f32x4){0.f, 0.f, 0.f, 0.f};

  int arow = tid >> 1;
  int acol = (tid & 1) * 16;
  int bn = tid & 127;
  int bkh = (tid >> 7) * 16;

  bool avalid;
  long long asrc;
  if constexpr (MODE == 0){
    avalid = (m0 + arow) < Me;
    int tok = avalid ? rowsl[roff + m0 + arow] : 0;
    asrc = (long long)tok * lda;
  } else if constexpr (MODE == 1){
    avalid = (m0 + arow) < Me;
    asrc = (long long)arow * lda;
  } else {
    avalid = true;
    asrc = (long long)(MODE == 2 ? (m0 + arow) : arow) * lda;
    if constexpr (MODE == 3) asrc = (long long)(m0 + arow) * lda;
  }

  for (int k0 = 0; k0 < K; k0 += 32){
    uint4 a0 = make_uint4(0,0,0,0), a1 = make_uint4(0,0,0,0);
    if (avalid){
      const uint4* ap = (const uint4*)(A + asrc + k0 + acol);
      a0 = ap[0]; a1 = ap[1];
    }
    unsigned short bl[16] __attribute__((aligned(16)));
    const float* bp = B + (long long)(k0 + bkh) * N + n0 + bn;
    #pragma unroll
    for (int j = 0; j < 16; j++) bl[j] = f2bf(bp[(long long)j * N]);
    __syncthreads();
    *(uint4*)&As[arow*40 + acol]     = a0;
    *(uint4*)&As[arow*40 + acol + 8] = a1;
    *(uint4*)&Bs[bn*40 + bkh]        = *(uint4*)&bl[0];
    *(uint4*)&Bs[bn*40 + bkh + 8]    = *(uint4*)&bl[8];
    __syncthreads();
    bf16x8v af[4], bfv[4];
    #pragma unroll
    for (int mi = 0; mi < 4; mi++) af[mi]  = *(const bf16x8v*)&As[(wr*64 + mi*16 + lrow)*40 + kgo];
    #pragma unroll
    for (int nj = 0; nj < 4; nj++) bfv[nj] = *(const bf16x8v*)&Bs[(wc*64 + nj*16 + lrow)*40 + kgo];
    #pragma unroll
    for (int mi = 0; mi < 4; mi++)
      #pragma unroll
      for (int nj = 0; nj < 4; nj++)
        acc[mi][nj] = __builtin_amdgcn_mfma_f32_16x16x32_bf16(af[mi], bfv[nj], acc[mi][nj], 0, 0, 0);
  }

  int crow = wr*64 + (lane >> 4) * 4;
  int ccol = n0 + wc*64 + (lane & 15);
  #pragma unroll
  for (int mi = 0; mi < 4; mi++){
    #pragma unroll
    for (int r = 0; r < 4; r++){
      int lr = crow + mi*16 + r;
      if constexpr (MODE == 0){
        if ((m0 + lr) < Me){
          long long gr = (long long)(roff + m0 + lr);
          #pragma unroll
          for (int nj = 0; nj < 4; nj++)
            Cb[gr * N + ccol + nj*16] = f2bf(acc[mi][nj][r]);
        }
      } else if constexpr (MODE == 1){
        if ((m0 + lr) < Me){
          int gr = roff + m0 + lr;
          int tok = rowsl[gr];
          float wgt = wrowl[gr];
          #pragma unroll
          for (int nj = 0; nj < 4; nj++)
            atomicAdd(&Cacc[(long long)tok * 512 + ccol + nj*16], wgt * acc[mi][nj][r]);
        }
      } else if constexpr (MODE == 2){
        long long gr = (long long)blockIdx.z * 4096 + m0 + lr;
        #pragma unroll
        for (int nj = 0; nj < 4; nj++)
          Cb[gr * N + ccol + nj*16] = f2bf(acc[mi][nj][r]);
      } else {
        #pragma unroll
        for (int nj = 0; nj < 4; nj++)
          atomicAdd(&Cacc[(long long)(m0 + lr) * 512 + ccol + nj*16], acc[mi][nj][r]);
      }
    }
  }
}

// ---------------- balance-loss scalars ----------------
__global__ void kscalars(const int* __restrict__ cnt, const float* __restrict__ sumP, float* __restrict__ o){
  int e = threadIdx.x;
  float cf = (float)cnt[e];
  float f = cf / 24576.0f;
  float P = sumP[e] / 4096.0f;
  float fg = f, Pg = P, cg = cf;
  fg += __shfl_xor(fg, 1); fg += __shfl_xor(fg, 2); fg += __shfl_xor(fg, 4);
  Pg += __shfl_xor(Pg, 1); Pg += __shfl_xor(Pg, 2); Pg += __shfl_xor(Pg, 4);
  cg += __shfl_xor(cg, 1); cg += __shfl_xor(cg, 2); cg += __shfl_xor(cg, 4);
  float t1 = f * P;
  float t2 = ((e & 7) == 0) ? (fg / 8.0f) * Pg : 0.0f;
  float t3 = ((e & 7) == 0) ? (cg / 12288.0f) * Pg : 0.0f;
  for (int s = 32; s > 0; s >>= 1){
    t1 += __shfl_xor(t1, s); t2 += __shfl_xor(t2, s); t3 += __shfl_xor(t3, s);
  }
  if (e == 0){
    float ebl = t1 * 0.003f, dbl = t2 * 0.05f, cbl = t3 * 0.02f;
    o[0] = ebl; o[1] = dbl; o[2] = cbl; o[3] = ebl + dbl + cbl;
  }
}

// ---------------- launch ----------------
extern "C" void kernel_launch(void* const* d_in, const int* in_sizes, int n_in,
                              void* d_out, int out_size, void* d_ws, size_t ws_size,
                              hipStream_t stream){
  const float* x        = (const float*)d_in[0];
  const float* cosb     = (const float*)d_in[1];
  const float* sinb     = (const float*)d_in[2];
  const float* w_qkv    = (const float*)d_in[3];
  const float* w_o      = (const float*)d_in[4];
  const float* router_w = (const float*)d_in[5];
  const float* r_wgu    = (const float*)d_in[6];
  const float* r_wd     = (const float*)d_in[7];
  const float* s_wgu    = (const float*)d_in[8];
  const float* s_wd     = (const float*)d_in[9];
  float* out = (float*)d_out;

  char* wsp = (char*)d_ws;
  auto alloc = [&](size_t bytes)->char*{
    char* p = wsp; wsp += (bytes + 255) & ~(size_t)255; return p;
  };
  float* qkv   = (float*)alloc(4096ULL*1536*4);
  float* vT    = (float*)alloc(32ULL*64*1024*4);
  float* wqkvT = (float*)alloc(1536ULL*512*4);
  float* woT   = (float*)alloc(512ULL*512*4);
  float* wrT   = (float*)alloc(64ULL*512*4);
  float* attno = (float*)alloc(4096ULL*512*4);
  float* attnw = (float*)alloc(4096ULL*512*4);
  float* h1    = (float*)alloc(4096ULL*512*4);
  unsigned short* h1b = (unsigned short*)alloc(4096ULL*512*2);
  float* macc  = (float*)alloc(4096ULL*512*4);
  float* logits= (float*)alloc(4096ULL*64*4);
  float* probs = (float*)alloc(4096ULL*64*4);
  int*   idx   = (int*)alloc(4096ULL*6*4);
  float* wts   = (float*)alloc(4096ULL*6*4);
  int*   cnt   = (int*)alloc(64*4);     // counters: cnt then cursor contiguous (512B memset)
  int*   cursor= (int*)alloc(64*4);
  int*   offs  = (int*)alloc(65*4);
  int*   ntl   = (int*)alloc(256);
  float* sumP  = (float*)alloc(64*4);
  int2*  tiles = (int2*)alloc(512*8);
  int*   rowsl = (int*)alloc(24576ULL*4);
  float* wrowl = (float*)alloc(24576ULL*4);
  // Aliased region: attention scores (128MB) reuses FFN gu/hact/sgu/shact space (~302MB).
  char* region = alloc(24576ULL*3072*2 + 24576ULL*1536*2 + 2ULL*4096*3072*2 + 2ULL*4096*1536*2);
  float* scores = (float*)region;
  unsigned short* gu    = (unsigned short*)region;
  unsigned short* hact  = (unsigned short*)(region + 24576ULL*3072*2);
  unsigned short* sgu   = (unsigned short*)(region + 24576ULL*3072*2 + 24576ULL*1536*2);
  unsigned short* shact = (unsigned short*)(region + 24576ULL*3072*2 + 24576ULL*1536*2 + 2ULL*4096*3072*2);

  hipMemsetAsync(cnt, 0, 512, stream);

  // small weight transposes (fp32)
  ktranspose<<<dim3(48, 16), 256, 0, stream>>>(w_qkv, wqkvT, 512, 1536);
  ktranspose<<<dim3(16, 16), 256, 0, stream>>>(w_o, woT, 512, 512);
  ktranspose<<<dim3(2, 16),  256, 0, stream>>>(router_w, wrT, 512, 64);

  // qkv = x @ w_qkv
  gemm_f32<<<dim3(64, 24, 1), 256, 0, stream>>>(x, wqkvT, qkv, 512, 512, 512, 1536, 1.0f,
      0,0,1, 0,0,1, 0,0,1);
  krope<<<4096, 256, 0, stream>>>(qkv, vT, cosb, sinb);
  // scores = (Q K^T)/8 per (b,h)
  gemm_f32<<<dim3(16, 16, 32), 256, 0, stream>>>(qkv, qkv + 512, scores, 64, 1536, 1536, 1024, 0.125f,
      (long long)1024*1536, 64, 8,
      (long long)1024*1536, 64, 8,
      (long long)1024*1024, 0, 1);
  ksoftmax<<<32768, 256, 0, stream>>>(scores);
  // O = P V
  gemm_f32<<<dim3(16, 1, 32), 256, 0, stream>>>(scores, vT, attno, 1024, 1024, 1024, 512, 1.0f,
      (long long)1024*1024, 0, 1,
      (long long)64*1024, 0, 1,
      (long long)1024*512, 64, 8);
  // attn = O @ w_o
  gemm_f32<<<dim3(64, 8, 1), 256, 0, stream>>>(attno, woT, attnw, 512, 512, 512, 512, 1.0f,
      0,0,1, 0,0,1, 0,0,1);
  krms1<<<4096, 128, 0, stream>>>(x, attnw, h1, h1b, macc);
  // router logits
  gemm_f32<<<dim3(64, 1, 1), 256, 0, stream>>>(h1, wrT, logits, 512, 512, 512, 64, 1.0f,
      0,0,1, 0,0,1, 0,0,1);
  krouter<<<1024, 256, 0, stream>>>(logits, probs, idx, wts, cnt);
  ksump<<<64, 256, 0, stream>>>(probs, sumP);
  kfinalize<<<1, 64, 0, stream>>>(cnt, offs, tiles, ntl);
  kscatter<<<96, 256, 0, stream>>>(idx, wts, offs, cursor, rowsl, wrowl);

  // expert gate/up GEMM (sparse, gathered rows)
  gemm_bf16<0><<<dim3(256, 24, 1), 256, 0, stream>>>(h1b, r_wgu, gu, nullptr,
      offs, tiles, ntl, rowsl, wrowl, 3072, 512);
  // shared gate/up
  gemm_bf16<2><<<dim3(32, 24, 2), 256, 0, stream>>>(h1b, s_wgu, sgu, nullptr,
      offs, tiles, ntl, rowsl, wrowl, 3072, 512);
  kact<<<(24576*192 + 255)/256, 256, 0, stream>>>(gu, hact, 24576*192);
  kact<<<(8192*192 + 255)/256, 256, 0, stream>>>(sgu, shact, 8192*192);
  // expert down (scatter-add weighted)
  gemm_bf16<1><<<dim3(256, 4, 1), 256, 0, stream>>>(hact, r_wd, nullptr, macc,
      offs, tiles, ntl, rowsl, wrowl, 512, 1536);
  // shared down (add)
  gemm_bf16<3><<<dim3(32, 4, 2), 256, 0, stream>>>(shact, s_wd, nullptr, macc,
      offs, tiles, ntl, rowsl, wrowl, 512, 1536);

  krms2<<<4096, 128, 0, stream>>>(macc, out);
  kscalars<<<1, 64, 0, stream>>>(cnt, sumP, out + 4096ULL*512);
}